// Round 8
// baseline (155.810 us; speedup 1.0000x reference)
//
#include <hip/hip_runtime.h>
#include <stdint.h>

typedef unsigned short u16;
typedef __attribute__((ext_vector_type(8))) short short8;   // 8 x bf16 (4 VGPRs)
typedef __attribute__((ext_vector_type(4))) float f32x4;    // 4 x fp32 acc

typedef __attribute__((address_space(3))) uint8_t* lds_ptr_t;
typedef const __attribute__((address_space(1))) uint8_t* gbl_ptr_t;

__device__ __forceinline__ u16 f2bf(float f) {
    union { float f; uint32_t u; } v; v.f = f;
    return (u16)((v.u + (0x7FFFu + ((v.u >> 16) & 1u))) >> 16);   // RNE
}

// ---------------- P1+P2 merged: W2 = U*S (bf16) | Vp = MFMA-packed V -----------
__global__ void k_prep(const float* __restrict__ U, const float* __restrict__ S,
                       u16* __restrict__ W2,
                       const float* __restrict__ V, u16* __restrict__ Vp) {
    int bx = blockIdx.x;
    if (bx < 64) {
        int t = bx * 256 + threadIdx.x;                // 16384 threads
        int o = t >> 6, j = t & 63;
        float acc = 0.f;
#pragma unroll 8
        for (int i = 0; i < 64; ++i) acc += U[o * 64 + i] * S[i * 64 + j];
        W2[t] = f2bf(acc);
    } else {
        int t = (bx - 64) * 256 + threadIdx.x;         // 18432 threads (72 blocks)
        int ln = t & 63, mt = (t >> 6) & 3, cc = (t >> 8) & 1;
        int tap = (t >> 9) % 9, kv = t / 4608;
        int r = mt * 16 + (ln & 15);
        int cb = kv * 64 + cc * 32 + (ln >> 4) * 8;
        u16 tmp[8];
#pragma unroll
        for (int e = 0; e < 8; ++e)
            tmp[e] = f2bf(V[(size_t)((cb + e) * 9 + tap) * 64 + r]);
        *(uint4*)(Vp + (size_t)t * 8) = *(uint4*)tmp;
    }
}

// ---------------- P3: coalesced LDS-tiled transpose+pad  -----------------------
// xb[b][hp][wp][c] (bf16, [16][58][58][256]) from x[b][c][h][w] fp32.
__global__ __launch_bounds__(256) void k_tr(const float* __restrict__ x,
                                            u16* __restrict__ xb) {
    __shared__ uint32_t lds[64 * 57];               // 14592 B
    int bi = blockIdx.x;                            // 16*58*2 = 1856
    int cg = bi & 1;
    int hp = (bi >> 1) % 58;
    int b  = bi / 116;
    int c0 = cg * 128;
    int tid = threadIdx.x;

    uint32_t* xbrow32 = (uint32_t*)(xb + ((size_t)(b * 58 + hp) * 58) * 256 + c0);

    if (hp == 0 || hp == 57) {                      // border row: all zeros
        for (int i = tid; i < 58 * 64; i += 256)
            xbrow32[(i >> 6) * 128 + (i & 63)] = 0u;
        return;
    }

    int h = hp - 1;
    int w = tid & 63;                               // 56 valid
    int cpq = tid >> 6;                             // 0..3
    const float* xbase = x + ((size_t)(b * 256 + c0) * 3136) + h * 56 + w;
    if (w < 56) {
#pragma unroll
        for (int k = 0; k < 16; ++k) {
            int cp = cpq * 16 + k;                  // channel pair 0..63
            float a0 = xbase[(size_t)(2 * cp) * 3136];
            float a1 = xbase[(size_t)(2 * cp + 1) * 3136];
            lds[cp * 57 + w] = (uint32_t)f2bf(a0) | ((uint32_t)f2bf(a1) << 16);
        }
    }
    __syncthreads();

    int cpair = tid & 63;
    int wpq = tid >> 6;
#pragma unroll
    for (int wp = wpq; wp < 58; wp += 4) {
        uint32_t v = (wp == 0 || wp == 57) ? 0u : lds[cpair * 57 + (wp - 1)];
        xbrow32[wp * 128 + cpair] = v;
    }
}

// ---------------- Stage A v12: wide-tile low-A-traffic conv --------------------
// DIAGNOSIS (r0-r7): conv wall time tracks fat-load count (per-CU TA/L1 line
// occupancy), not latency/occupancy/barriers. Dominant term: A-frag traffic =
// 288KB/block x 784 blocks = 226MB re-read of a 294KB matrix. A-bytes/pixel ~
// 1/(px per wave) -> widen the per-wave tile.
// v12: 14x8 tile (112 px), nt=7, 448 blocks (=8*56, XCD-swizzled).
//   - A-traffic 226 -> 129 MB (-43% of the dominant term)
//   - full 16x10x256c window staged upfront (80KB, both c-phases resident):
//     ONE barrier, then 18 uninterrupted k-steps
//   - 256B cells [ph][cell][128c]: bv reads are quad-broadcast, 16-chunk XOR
//     swizzle -> near-zero bank conflicts (vs 1.15M)
//   - stage deduped: 80 x 1KB split across 4 waves (20 each)
__global__ __launch_bounds__(256, 2) void k_conv(const u16* __restrict__ xb,
                                                 const u16* __restrict__ Vp,
                                                 u16* __restrict__ y1) {
    __shared__ u16 lds[40960];                      // 81920 B = 2 ph x 160 cells x 256B
    int bi0 = blockIdx.x;                           // 448 = 8 * 56
    int bi = (bi0 & 7) * 56 + (bi0 >> 3);           // XCD-chunked swizzle (bijective)
    int wt = bi % 7, ht = (bi / 7) % 4, b = bi / 28;
    int h0 = ht * 14, w0 = wt * 8;                  // 4x7 tiles of 14x8 = 56x56
    int tid = threadIdx.x;
    int kv = tid >> 6, ln = tid & 63;
    int lane15 = ln & 15, quad = ln >> 4;
    int dh = lane15 >> 3, dw = lane15 & 7;          // dh 0..1, dw 0..7

    // ---- stage: 80 x 1KB instrs split across waves (wave kv: i = kv+4t).
    // instr i covers cells 4(i%40)..+3 of phase i/40; lane ln: cell = base+(ln>>4),
    // slot = ln&15; LDS dest linear (uniform base + lane*16); source pre-swizzled:
    // chunk = slot ^ (cell&15)  (cell&15 invariant across t for fixed lane).
    {
        int slot = ln & 15;
        int cell0 = kv * 4 + (ln >> 4);             // 0..15
        int chunk = slot ^ cell0;                   // constant per lane
        const u16* gw = xb + (((size_t)(b * 58 + h0)) * 58 + w0) * 256;
        char* lb = (char*)lds;
#pragma unroll
        for (int ph = 0; ph < 2; ++ph) {
            int rr = (cell0 >= 10) ? 1 : 0;
            int wp = cell0 - rr * 10;
            const u16* gph = gw + ph * 128 + chunk * 8;
            char* dph = lb + ph * 40960;
            for (int t = 0; t < 10; ++t) {
                const u16* g = gph + (rr * 58 + wp) * 256;
                __builtin_amdgcn_global_load_lds((gbl_ptr_t)g,
                    (lds_ptr_t)(dph + (kv + 4 * t) * 1024), 16, 0, 0);
                // cell += 16  ->  wp += 16 (= +10 carry +6)
                wp += 6; rr += 1;
                if (wp >= 10) { wp -= 10; rr += 1; }
            }
        }
    }
    __syncthreads();

    // ---- K-loop: 18 k-steps (2 ph x 9 taps), 28 MFMA each, no barriers ----
    const char* lb = (const char*)lds;
    int jchunk = (kv << 2) + quad;                  // chunk index of this wave's 32c

    f32x4 acc[4][7];
#pragma unroll
    for (int mt = 0; mt < 4; ++mt)
#pragma unroll
        for (int nt = 0; nt < 7; ++nt) acc[mt][nt] = (f32x4){0.f, 0.f, 0.f, 0.f};

#pragma unroll
    for (int s = 0; s < 18; ++s) {
        const int ph = (s >= 9) ? 1 : 0;
        const int tap = s - ph * 9;
        const int di = tap / 3, dj = tap % 3;
        // A-frag: channels ph*128 + kv*32 -> kvv = ph*2 + (kv>>1), cc = kv&1
        const int kvv = ph * 2 + (kv >> 1), cc = kv & 1;
        const u16* ab = Vp + ((size_t)(((kvv * 9 + tap) * 2 + cc) * 4) * 512)
                      + ln * 8;
        short8 a[4];
#pragma unroll
        for (int mt = 0; mt < 4; ++mt)
            a[mt] = *(const short8*)(ab + mt * 512);
#pragma unroll
        for (int nt = 0; nt < 7; ++nt) {
            int cell = (nt * 2 + dh + di) * 10 + (dw + dj);
            short8 bv = *(const short8*)(lb + ph * 40960 + cell * 256
                                         + ((jchunk ^ (cell & 15)) << 4));
#pragma unroll
            for (int mt = 0; mt < 4; ++mt)
                acc[mt][nt] = __builtin_amdgcn_mfma_f32_16x16x32_bf16(
                    a[mt], bv, acc[mt][nt], 0, 0, 0);
        }
    }

    // ---- 4-way K-split reduction into wave 0 (reuse LDS; 57344B <= 81920B) ----
    __syncthreads();                                // all ds_reads of x done
    f32x4* red = (f32x4*)lds;
    if (kv & 1) {                                   // kv1 -> red[0..27], kv3 -> [28..55]
        f32x4* dst = red + ((kv >> 1) * 28) * 64;
#pragma unroll
        for (int mt = 0; mt < 4; ++mt)
#pragma unroll
            for (int nt = 0; nt < 7; ++nt)
                dst[(mt * 7 + nt) * 64 + ln] = acc[mt][nt];
    }
    __syncthreads();
    if (kv == 0) {
#pragma unroll
        for (int mt = 0; mt < 4; ++mt)
#pragma unroll
            for (int nt = 0; nt < 7; ++nt)
                acc[mt][nt] += red[(mt * 7 + nt) * 64 + ln];
    } else if (kv == 2) {
#pragma unroll
        for (int mt = 0; mt < 4; ++mt)
#pragma unroll
            for (int nt = 0; nt < 7; ++nt)
                red[(28 + mt * 7 + nt) * 64 + ln] += acc[mt][nt];
    }
    __syncthreads();
    if (kv == 0) {
#pragma unroll
        for (int mt = 0; mt < 4; ++mt)
#pragma unroll
            for (int nt = 0; nt < 7; ++nt) {
                f32x4 v = acc[mt][nt] + red[(28 + mt * 7 + nt) * 64 + ln];
                int oh = nt * 2 + dh, ow = dw;      // oh 0..13
                int l = b * 3136 + (h0 + oh) * 56 + (w0 + ow);
                uint2 pv;
                pv.x = (uint32_t)f2bf(v[0]) | ((uint32_t)f2bf(v[1]) << 16);
                pv.y = (uint32_t)f2bf(v[2]) | ((uint32_t)f2bf(v[3]) << 16);
                *(uint2*)(y1 + ((size_t)l << 6) + mt * 16 + quad * 4) = pv;
            }
    }
}

// ---------------- Stage B: out[b][o][l] = W2[o][:] . y1[b][l][:] + bias[o] -----
__global__ __launch_bounds__(256) void k_gemmB(const u16* __restrict__ y1,
                                               const u16* __restrict__ W2,
                                               const float* __restrict__ bias,
                                               float* __restrict__ out) {
    __shared__ u16 lds_y[64 * 72];                  // 9216 B
    int bi = blockIdx.x;                            // 784 = 16*49
    int b = bi % 16, lt = bi / 16;
    int l0 = lt * 64;
    int tid = threadIdx.x;
    int wv = tid >> 6, ln = tid & 63;
    int lane15 = ln & 15, quad = ln >> 4;

    for (int idx = tid; idx < 512; idx += 256) {
        int q = idx & 7, n = idx >> 3;
        uint4 v = *(const uint4*)(y1 + (((size_t)(b * 3136 + l0 + n)) << 6) + q * 8);
        *(uint4*)&lds_y[n * 72 + q * 8] = v;
    }
    __syncthreads();

    f32x4 acc[4][4];
#pragma unroll
    for (int mt = 0; mt < 4; ++mt)
#pragma unroll
        for (int nt = 0; nt < 4; ++nt) acc[mt][nt] = (f32x4){0.f, 0.f, 0.f, 0.f};

    int o0 = wv * 64;
#pragma unroll
    for (int ks = 0; ks < 64; ks += 32) {
        short8 a[4];
#pragma unroll
        for (int mt = 0; mt < 4; ++mt)
            a[mt] = *(const short8*)(W2 + (size_t)(o0 + mt * 16 + lane15) * 64
                                     + ks + quad * 8);
#pragma unroll
        for (int nt = 0; nt < 4; ++nt) {
            short8 bv = *(const short8*)&lds_y[(nt * 16 + lane15) * 72 + ks + quad * 8];
#pragma unroll
            for (int mt = 0; mt < 4; ++mt)
                acc[mt][nt] = __builtin_amdgcn_mfma_f32_16x16x32_bf16(a[mt], bv, acc[mt][nt], 0, 0, 0);
        }
    }

#pragma unroll
    for (int mt = 0; mt < 4; ++mt) {
        int ob = o0 + mt * 16 + quad * 4;
#pragma unroll
        for (int reg = 0; reg < 4; ++reg) {
            int o = ob + reg;
            float bvl = bias[o];
            float* orow = out + ((size_t)(b * 256 + o)) * 3136 + l0 + lane15;
#pragma unroll
            for (int nt = 0; nt < 4; ++nt)
                orow[nt * 16] = acc[mt][nt][reg] + bvl;
        }
    }
}

extern "C" void kernel_launch(void* const* d_in, const int* in_sizes, int n_in,
                              void* d_out, int out_size, void* d_ws, size_t ws_size,
                              hipStream_t stream) {
    const float* x    = (const float*)d_in[0];   // [16,256,56,56]
    const float* U    = (const float*)d_in[1];   // [256,64]
    const float* S    = (const float*)d_in[2];   // [64,64]
    const float* V    = (const float*)d_in[3];   // [2304,64]
    const float* bias = (const float*)d_in[4];   // [256]
    float* out = (float*)d_out;                  // [16,256,56,56] fp32

    char* ws = (char*)d_ws;
    u16* xb = (u16*)ws;                                   // 27,557,888 B
    u16* Vp = (u16*)(ws + 27557888);                      //    294,912 B
    u16* W2 = (u16*)(ws + 27557888 + 294912);             //     32,768 B
    u16* y1 = (u16*)(ws + 27557888 + 294912 + 32768);     //  6,422,528 B

    k_prep <<<136,  256, 0, stream>>>(U, S, W2, V, Vp);
    k_tr   <<<1856, 256, 0, stream>>>(x, xb);
    k_conv <<<448,  256, 0, stream>>>(xb, Vp, y1);
    k_gemmB<<<784,  256, 0, stream>>>(y1, W2, bias, out);
}